// Round 4
// baseline (91.837 us; speedup 1.0000x reference)
//
#include <hip/hip_runtime.h>
#include <hip/hip_bf16.h>

#define BB 2
#define NN 1024
#define MM 1024
#define DD 256
#define HH 128
#define C2LE 2.8853900817779268f   // 2*log2(e)
#define LOG2E 1.4426950408889634f
#define ROWS 16

// ---- Kernel 1: Ea = exp2(C*(q@Wa+ba)), Eb = exp2(C*(k@Wb+bb)), C=2*log2(e)
__global__ __launch_bounds__(256) void proj_kernel(
    const float* __restrict__ query, const float* __restrict__ key,
    const float* __restrict__ Wa_w, const float* __restrict__ Wa_b,
    const float* __restrict__ Wb_w, const float* __restrict__ Wb_b,
    float* __restrict__ Ea, float* __restrict__ Eb) {
    __shared__ float rows[8][DD];     // 8KB
    __shared__ float partial[8][HH];  // 4KB
    const int tid = threadIdx.x;
    const int rb = blockIdx.x * 8;
    const bool isA = rb < BB * NN;
    const float* in = isA ? query : key;
    const float* W  = isA ? Wa_w : Wb_w;
    const float* bias = isA ? Wa_b : Wb_b;
    float* outp = isA ? Ea : Eb;
    const int base = isA ? rb : rb - BB * NN;

    const float4* in4 = (const float4*)(in + (size_t)base * DD);
    float4* rows4 = (float4*)rows;
    rows4[tid] = in4[tid];
    rows4[tid + 256] = in4[tid + 256];
    __syncthreads();

    const int h = tid & 127, half = tid >> 7;
    const int d0 = half * 128;
    float acc[8] = {};
    for (int d = d0; d < d0 + 128; d += 4) {
        const float w0 = W[(d + 0) * HH + h];
        const float w1 = W[(d + 1) * HH + h];
        const float w2 = W[(d + 2) * HH + h];
        const float w3 = W[(d + 3) * HH + h];
#pragma unroll
        for (int r = 0; r < 8; ++r) {
            const float4 rv = *(const float4*)&rows[r][d];
            acc[r] = fmaf(rv.x, w0, fmaf(rv.y, w1, fmaf(rv.z, w2, fmaf(rv.w, w3, acc[r]))));
        }
    }
    if (half) {
#pragma unroll
        for (int r = 0; r < 8; ++r) partial[r][h] = acc[r];
    }
    __syncthreads();
    if (!half) {
        const float bv = bias[h];
#pragma unroll
        for (int r = 0; r < 8; ++r)
            outp[(size_t)(base + r) * HH + h] =
                __builtin_amdgcn_exp2f(C2LE * (acc[r] + partial[r][h] + bv));
    }
}

// ---- Kernel 2: P[b,n,m] = exp( sum_h w_h / (Ea_h*Eb_h + 1) ), w = -2v
//      (unnormalized; +sum(v) constant dropped — softmax shift-invariant)
//      4 h-terms share one rcp: sum wi/ui = (sum wi*prod_{j!=i} uj)/(prod uj)
__global__ __launch_bounds__(256) void scores_kernel(
    const float* __restrict__ Ea, const float* __restrict__ Eb,
    const float* __restrict__ v_w, float* __restrict__ P) {
    __shared__ float a_t[32][HH];   // 16KB broadcast reads
    __shared__ float b_s[64 * HH];  // 32KB, XOR-swizzled rows
    __shared__ float w_s[HH];       // -2*v
    const int tid = threadIdx.x;
    const int m0 = blockIdx.x * 64, n0 = blockIdx.y * 32, b = blockIdx.z;

    for (int i = tid; i < 32 * 32; i += 256) {
        const int r = i >> 5, h4 = i & 31;
        *(float4*)&a_t[r][h4 * 4] =
            *(const float4*)&Ea[((size_t)(b * NN + n0 + r)) * HH + h4 * 4];
    }
    for (int i = tid; i < 64 * 32; i += 256) {
        const int r = i >> 5, h4 = i & 31;
        *(float4*)&b_s[r * HH + ((h4 ^ (r & 7)) << 2)] =
            *(const float4*)&Eb[((size_t)(b * MM + m0 + r)) * HH + h4 * 4];
    }
    if (tid < HH) w_s[tid] = -2.0f * v_w[tid];
    __syncthreads();

    const int ml = tid & 63, ng = tid >> 6;
    const int mlx = ml & 7;
    const float* brow = &b_s[ml * HH];
    float acc[8] = {};
    for (int h4 = 0; h4 < 32; ++h4) {
        const float4 w4 = *(const float4*)&w_s[h4 * 4];            // broadcast
        const float4 b4 = *(const float4*)&brow[(h4 ^ mlx) << 2];  // swizzled
#pragma unroll
        for (int i = 0; i < 8; ++i) {
            const float4 a4 = *(const float4*)&a_t[ng * 8 + i][h4 * 4];  // broadcast
            const float u0 = fmaf(a4.x, b4.x, 1.0f);
            const float u1 = fmaf(a4.y, b4.y, 1.0f);
            const float u2 = fmaf(a4.z, b4.z, 1.0f);
            const float u3 = fmaf(a4.w, b4.w, 1.0f);
            const float p01 = u0 * u1, p23 = u2 * u3;
            float An = w4.x * u1;  An = fmaf(w4.y, u0, An);
            float Bn = w4.z * u3;  Bn = fmaf(w4.w, u2, Bn);
            float num = An * p23;  num = fmaf(Bn, p01, num);
            acc[i] = fmaf(num, __builtin_amdgcn_rcpf(p01 * p23), acc[i]);
        }
    }

    const size_t rowbase = (size_t)b * NN * MM + (size_t)n0 * MM + m0 + ml;
#pragma unroll
    for (int i = 0; i < 8; ++i)
        P[rowbase + (size_t)(ng * 8 + i) * MM] =
            __builtin_amdgcn_exp2f(acc[i] * LOG2E);  // coalesced
}

// ---- Kernel 3: out[n,d] = (sum_m P[n,m]*K[m,d]) / (sum_m P[n,m]) ----------
// Block = 16 n-rows x 64-col d-quarter x all m. Cuts L2 key traffic 4x.
__global__ __launch_bounds__(512) void attend_kernel(
    const float* __restrict__ P, const float* __restrict__ key,
    float* __restrict__ out) {
    __shared__ float p[ROWS][MM];  // 64KB unnormalized probs
    __shared__ float sums[ROWS];
    const int tid = threadIdx.x;
    const int d0 = blockIdx.x * 64;
    const int n0 = blockIdx.y * ROWS;
    const int b  = blockIdx.z;
    const int wave = tid >> 6, lane = tid & 63;

    // stage P tile (4096 float4, coalesced)
    const float4* Pg = (const float4*)(P + ((size_t)b * NN + n0) * MM);
    float4* pl = (float4*)p;
#pragma unroll
    for (int k = 0; k < 8; ++k) pl[tid + k * 512] = Pg[tid + k * 512];
    __syncthreads();

    // row sums: wave w -> rows 2w, 2w+1 (scalar LDS reads, bank-conflict-free)
#pragma unroll
    for (int j = 0; j < 2; ++j) {
        const int r = wave * 2 + j;
        float s = 0.f;
#pragma unroll
        for (int k = 0; k < 16; ++k) s += p[r][lane + 64 * k];
#pragma unroll
        for (int o = 32; o > 0; o >>= 1) s += __shfl_xor(s, o);
        if (lane == 0) sums[r] = s;
    }
    __syncthreads();

    // PV: wave rg covers rows 2rg,2rg+1; lane = d within quarter
    const int r0 = wave * 2, r1 = r0 + 1;
    const float* kb = key + (size_t)b * MM * DD + d0 + lane;
    float acc0 = 0.f, acc1 = 0.f;
#pragma unroll 4
    for (int m = 0; m < MM; m += 2) {
        const float k0 = kb[(size_t)(m + 0) * DD];
        const float k1 = kb[(size_t)(m + 1) * DD];
        const float2 p0 = *(const float2*)&p[r0][m];  // broadcast
        const float2 p1 = *(const float2*)&p[r1][m];  // broadcast
        acc0 = fmaf(p0.x, k0, fmaf(p0.y, k1, acc0));
        acc1 = fmaf(p1.x, k0, fmaf(p1.y, k1, acc1));
    }
    const size_t ob = ((size_t)b * NN + n0) * DD + d0 + lane;
    out[ob + (size_t)r0 * DD] = acc0 * (1.0f / sums[r0]);
    out[ob + (size_t)r1 * DD] = acc1 * (1.0f / sums[r1]);
}

extern "C" void kernel_launch(void* const* d_in, const int* in_sizes, int n_in,
                              void* d_out, int out_size, void* d_ws, size_t ws_size,
                              hipStream_t stream) {
    const float* query = (const float*)d_in[0];
    const float* key   = (const float*)d_in[1];
    const float* Wa_w  = (const float*)d_in[2];
    const float* Wa_b  = (const float*)d_in[3];
    const float* Wb_w  = (const float*)d_in[4];
    const float* Wb_b  = (const float*)d_in[5];
    const float* v_w   = (const float*)d_in[6];
    float* out = (float*)d_out;

    float* ws = (float*)d_ws;
    float* Ea = ws;                       // B*N*H floats
    float* Eb = Ea + BB * NN * HH;        // B*M*H floats
    float* P  = Eb + BB * MM * HH;        // B*N*M floats (10MB total)

    proj_kernel<<<dim3((BB * NN + BB * MM) / 8), dim3(256), 0, stream>>>(
        query, key, Wa_w, Wa_b, Wb_w, Wb_b, Ea, Eb);
    scores_kernel<<<dim3(MM / 64, NN / 32, BB), dim3(256), 0, stream>>>(
        Ea, Eb, v_w, P);
    attend_kernel<<<dim3(DD / 64, NN / ROWS, BB), dim3(512), 0, stream>>>(
        P, key, out);
}

// Round 5
// 73.029 us; speedup vs baseline: 1.2575x; 1.2575x over previous
//
#include <hip/hip_runtime.h>
#include <hip/hip_bf16.h>

#define BB 2
#define NN 1024
#define MM 1024
#define DD 256
#define HH 128
#define C2LE 2.8853900817779268f   // 2*log2(e)
#define LOG2E 1.4426950408889634f
#define ARO 32                     // attend rows per block

// ---- Kernel 1: Ea = exp2(C*(q@Wa+ba)), Eb = exp2(C*(k@Wb+bb)), C=2*log2(e)
__global__ __launch_bounds__(256) void proj_kernel(
    const float* __restrict__ query, const float* __restrict__ key,
    const float* __restrict__ Wa_w, const float* __restrict__ Wa_b,
    const float* __restrict__ Wb_w, const float* __restrict__ Wb_b,
    float* __restrict__ Ea, float* __restrict__ Eb) {
    __shared__ float rows[8][DD];     // 8KB
    __shared__ float partial[8][HH];  // 4KB
    const int tid = threadIdx.x;
    const int rb = blockIdx.x * 8;
    const bool isA = rb < BB * NN;
    const float* in = isA ? query : key;
    const float* W  = isA ? Wa_w : Wb_w;
    const float* bias = isA ? Wa_b : Wb_b;
    float* outp = isA ? Ea : Eb;
    const int base = isA ? rb : rb - BB * NN;

    const float4* in4 = (const float4*)(in + (size_t)base * DD);
    float4* rows4 = (float4*)rows;
    rows4[tid] = in4[tid];
    rows4[tid + 256] = in4[tid + 256];
    __syncthreads();

    const int h = tid & 127, half = tid >> 7;
    const int d0 = half * 128;
    float acc[8] = {};
    for (int d = d0; d < d0 + 128; d += 4) {
        const float w0 = W[(d + 0) * HH + h];
        const float w1 = W[(d + 1) * HH + h];
        const float w2 = W[(d + 2) * HH + h];
        const float w3 = W[(d + 3) * HH + h];
#pragma unroll
        for (int r = 0; r < 8; ++r) {
            const float4 rv = *(const float4*)&rows[r][d];
            acc[r] = fmaf(rv.x, w0, fmaf(rv.y, w1, fmaf(rv.z, w2, fmaf(rv.w, w3, acc[r]))));
        }
    }
    if (half) {
#pragma unroll
        for (int r = 0; r < 8; ++r) partial[r][h] = acc[r];
    }
    __syncthreads();
    if (!half) {
        const float bv = bias[h];
#pragma unroll
        for (int r = 0; r < 8; ++r)
            outp[(size_t)(base + r) * HH + h] =
                __builtin_amdgcn_exp2f(C2LE * (acc[r] + partial[r][h] + bv));
    }
}

// ---- Kernel 2: P[b,n,m] = exp( sum_h w_h / (Ea_h*Eb_h + 1) ), w = -2v
//      (unnormalized; constant dropped). 4 h-terms share one rcp.
__global__ __launch_bounds__(256) void scores_kernel(
    const float* __restrict__ Ea, const float* __restrict__ Eb,
    const float* __restrict__ v_w, float* __restrict__ P) {
    __shared__ float a_t[32][HH];   // 16KB broadcast reads
    __shared__ float b_s[64 * HH];  // 32KB, XOR-swizzled rows
    __shared__ float w_s[HH];       // -2*v
    const int tid = threadIdx.x;
    const int m0 = blockIdx.x * 64, n0 = blockIdx.y * 32, b = blockIdx.z;

    for (int i = tid; i < 32 * 32; i += 256) {
        const int r = i >> 5, h4 = i & 31;
        *(float4*)&a_t[r][h4 * 4] =
            *(const float4*)&Ea[((size_t)(b * NN + n0 + r)) * HH + h4 * 4];
    }
    for (int i = tid; i < 64 * 32; i += 256) {
        const int r = i >> 5, h4 = i & 31;
        *(float4*)&b_s[r * HH + ((h4 ^ (r & 7)) << 2)] =
            *(const float4*)&Eb[((size_t)(b * MM + m0 + r)) * HH + h4 * 4];
    }
    if (tid < HH) w_s[tid] = -2.0f * v_w[tid];
    __syncthreads();

    const int ml = tid & 63, ng = tid >> 6;
    const int mlx = ml & 7;
    const float* brow = &b_s[ml * HH];
    float acc[8] = {};
    for (int h4 = 0; h4 < 32; ++h4) {
        const float4 w4 = *(const float4*)&w_s[h4 * 4];            // broadcast
        const float4 b4 = *(const float4*)&brow[(h4 ^ mlx) << 2];  // swizzled
#pragma unroll
        for (int i = 0; i < 8; ++i) {
            const float4 a4 = *(const float4*)&a_t[ng * 8 + i][h4 * 4];  // broadcast
            const float u0 = fmaf(a4.x, b4.x, 1.0f);
            const float u1 = fmaf(a4.y, b4.y, 1.0f);
            const float u2 = fmaf(a4.z, b4.z, 1.0f);
            const float u3 = fmaf(a4.w, b4.w, 1.0f);
            const float p01 = u0 * u1, p23 = u2 * u3;
            float An = w4.x * u1;  An = fmaf(w4.y, u0, An);
            float Bn = w4.z * u3;  Bn = fmaf(w4.w, u2, Bn);
            float num = An * p23;  num = fmaf(Bn, p01, num);
            acc[i] = fmaf(num, __builtin_amdgcn_rcpf(p01 * p23), acc[i]);
        }
    }

    const size_t rowbase = (size_t)b * NN * MM + (size_t)n0 * MM + m0 + ml;
#pragma unroll
    for (int i = 0; i < 8; ++i)
        P[rowbase + (size_t)(ng * 8 + i) * MM] =
            __builtin_amdgcn_exp2f(acc[i] * LOG2E);  // coalesced
}

// ---- Kernel 3: PV over an m-quarter. Block = 32 rows x (MM/NQ) m x all d.
// Wave w owns rows 4w..4w+3; lane owns d = lane*4..+4 (float4 k loads).
// 16 fma per k-load; __syncthreads every 32 m keeps waves L1-converged.
template <int NQ>
__global__ __launch_bounds__(512) void attend_kernel(
    const float* __restrict__ P, const float* __restrict__ key,
    float* __restrict__ partial, float* __restrict__ psums,
    float* __restrict__ out) {
    constexpr int MQ = MM / NQ;
    __shared__ float p[ARO][MQ];
    __shared__ float rs[ARO];
    const int tid = threadIdx.x;
    const int wave = tid >> 6, lane = tid & 63;
    const int n0 = blockIdx.x * ARO;
    const int mq = blockIdx.y;
    const int b  = blockIdx.z;
    const int m0 = mq * MQ;

    // stage P tile + row sums: wave w -> rows 4w..4w+3
#pragma unroll
    for (int i = 0; i < 4; ++i) {
        const int r = wave * 4 + i;
        float s = 0.f;
#pragma unroll
        for (int c = 0; c < MQ / 256; ++c) {
            const float4 v = *(const float4*)
                &P[((size_t)(b * NN + n0 + r)) * MM + m0 + c * 256 + lane * 4];
            *(float4*)&p[r][c * 256 + lane * 4] = v;
            s += (v.x + v.y) + (v.z + v.w);
        }
#pragma unroll
        for (int o = 32; o > 0; o >>= 1) s += __shfl_xor(s, o);
        if (lane == 0) {
            if (NQ > 1) psums[((size_t)mq * BB + b) * NN + n0 + r] = s;
            else rs[r] = s;
        }
    }
    __syncthreads();

    const int r0 = wave * 4;
    const float* kb = key + ((size_t)b * MM + m0) * DD + lane * 4;
    float4 a0 = {0, 0, 0, 0}, a1 = a0, a2 = a0, a3 = a0;
    for (int mo = 0; mo < MQ; mo += 32) {
#pragma unroll 8
        for (int mi = 0; mi < 32; ++mi) {
            const int m = mo + mi;
            const float4 k4 = *(const float4*)&kb[(size_t)m * DD];
            const float p0 = p[r0 + 0][m];  // LDS broadcasts
            const float p1 = p[r0 + 1][m];
            const float p2 = p[r0 + 2][m];
            const float p3 = p[r0 + 3][m];
            a0.x = fmaf(p0, k4.x, a0.x); a0.y = fmaf(p0, k4.y, a0.y);
            a0.z = fmaf(p0, k4.z, a0.z); a0.w = fmaf(p0, k4.w, a0.w);
            a1.x = fmaf(p1, k4.x, a1.x); a1.y = fmaf(p1, k4.y, a1.y);
            a1.z = fmaf(p1, k4.z, a1.z); a1.w = fmaf(p1, k4.w, a1.w);
            a2.x = fmaf(p2, k4.x, a2.x); a2.y = fmaf(p2, k4.y, a2.y);
            a2.z = fmaf(p2, k4.z, a2.z); a2.w = fmaf(p2, k4.w, a2.w);
            a3.x = fmaf(p3, k4.x, a3.x); a3.y = fmaf(p3, k4.y, a3.y);
            a3.z = fmaf(p3, k4.z, a3.z); a3.w = fmaf(p3, k4.w, a3.w);
        }
        __syncthreads();  // keep waves converged so k-loads hit L1
    }

    if (NQ > 1) {
        const size_t base = (((size_t)mq * BB + b) * NN + n0 + r0) * DD + lane * 4;
        *(float4*)&partial[base + 0 * DD] = a0;
        *(float4*)&partial[base + 1 * DD] = a1;
        *(float4*)&partial[base + 2 * DD] = a2;
        *(float4*)&partial[base + 3 * DD] = a3;
    } else {
        const size_t base = ((size_t)b * NN + n0 + r0) * DD + lane * 4;
        const float i0 = __builtin_amdgcn_rcpf(rs[r0 + 0]);
        const float i1 = __builtin_amdgcn_rcpf(rs[r0 + 1]);
        const float i2 = __builtin_amdgcn_rcpf(rs[r0 + 2]);
        const float i3 = __builtin_amdgcn_rcpf(rs[r0 + 3]);
        a0.x *= i0; a0.y *= i0; a0.z *= i0; a0.w *= i0;
        a1.x *= i1; a1.y *= i1; a1.z *= i1; a1.w *= i1;
        a2.x *= i2; a2.y *= i2; a2.z *= i2; a2.w *= i2;
        a3.x *= i3; a3.y *= i3; a3.z *= i3; a3.w *= i3;
        *(float4*)&out[base + 0 * DD] = a0;
        *(float4*)&out[base + 1 * DD] = a1;
        *(float4*)&out[base + 2 * DD] = a2;
        *(float4*)&out[base + 3 * DD] = a3;
    }
}

// ---- Kernel 4: out[b,n,d] = sum_q partial[q][b,n,d] / sum_q psums[q][b,n]
template <int NQ>
__global__ __launch_bounds__(256) void combine_kernel(
    const float* __restrict__ partial, const float* __restrict__ psums,
    float* __restrict__ out) {
    const int n = blockIdx.x, b = blockIdx.y, d = threadIdx.x;
    float s = 0.f, a = 0.f;
#pragma unroll
    for (int q = 0; q < NQ; ++q) {
        s += psums[((size_t)q * BB + b) * NN + n];
        a += partial[(((size_t)q * BB + b) * NN + n) * DD + d];
    }
    out[((size_t)b * NN + n) * DD + d] = a * __builtin_amdgcn_rcpf(s);
}

extern "C" void kernel_launch(void* const* d_in, const int* in_sizes, int n_in,
                              void* d_out, int out_size, void* d_ws, size_t ws_size,
                              hipStream_t stream) {
    const float* query = (const float*)d_in[0];
    const float* key   = (const float*)d_in[1];
    const float* Wa_w  = (const float*)d_in[2];
    const float* Wa_b  = (const float*)d_in[3];
    const float* Wb_w  = (const float*)d_in[4];
    const float* Wb_b  = (const float*)d_in[5];
    const float* v_w   = (const float*)d_in[6];
    float* out = (float*)d_out;

    float* ws = (float*)d_ws;
    float* Ea = ws;                             // B*N*H
    float* Eb = Ea + BB * NN * HH;              // B*M*H
    float* P  = Eb + BB * MM * HH;              // B*N*M
    float* partial = P + (size_t)BB * NN * MM;  // 4*B*N*D
    float* psums   = partial + (size_t)4 * BB * NN * DD;  // 4*B*N
    const size_t need_bytes =
        ((size_t)(BB * NN * HH) + BB * MM * HH + (size_t)BB * NN * MM +
         (size_t)4 * BB * NN * DD + (size_t)4 * BB * NN) * sizeof(float);

    proj_kernel<<<dim3((BB * NN + BB * MM) / 8), dim3(256), 0, stream>>>(
        query, key, Wa_w, Wa_b, Wb_w, Wb_b, Ea, Eb);
    scores_kernel<<<dim3(MM / 64, NN / 32, BB), dim3(256), 0, stream>>>(
        Ea, Eb, v_w, P);
    if (ws_size >= need_bytes) {
        attend_kernel<4><<<dim3(NN / ARO, 4, BB), dim3(512), 0, stream>>>(
            P, key, partial, psums, out);
        combine_kernel<4><<<dim3(NN, BB), dim3(256), 0, stream>>>(
            partial, psums, out);
    } else {
        attend_kernel<1><<<dim3(NN / ARO, 1, BB), dim3(512), 0, stream>>>(
            P, key, partial, psums, out);
    }
}

// Round 6
// 67.623 us; speedup vs baseline: 1.3581x; 1.0799x over previous
//
#include <hip/hip_runtime.h>
#include <hip/hip_bf16.h>

#define BB 2
#define NN 1024
#define MM 1024
#define DD 256
#define HH 128
#define C2LE 2.8853900817779268f   // 2*log2(e)
#define LOG2E 1.4426950408889634f
#define ARO 32                     // attend rows per block

typedef float v2f __attribute__((ext_vector_type(2)));
typedef float v4f __attribute__((ext_vector_type(4)));

// ---- Kernel 1: Ea = exp2(C*(q@Wa+ba)), Eb = exp2(C*(k@Wb+bb)), C=2*log2(e)
__global__ __launch_bounds__(256) void proj_kernel(
    const float* __restrict__ query, const float* __restrict__ key,
    const float* __restrict__ Wa_w, const float* __restrict__ Wa_b,
    const float* __restrict__ Wb_w, const float* __restrict__ Wb_b,
    float* __restrict__ Ea, float* __restrict__ Eb) {
    __shared__ float rows[8][DD];     // 8KB
    __shared__ float partial[8][HH];  // 4KB
    const int tid = threadIdx.x;
    const int rb = blockIdx.x * 8;
    const bool isA = rb < BB * NN;
    const float* in = isA ? query : key;
    const float* W  = isA ? Wa_w : Wb_w;
    const float* bias = isA ? Wa_b : Wb_b;
    float* outp = isA ? Ea : Eb;
    const int base = isA ? rb : rb - BB * NN;

    const float4* in4 = (const float4*)(in + (size_t)base * DD);
    float4* rows4 = (float4*)rows;
    rows4[tid] = in4[tid];
    rows4[tid + 256] = in4[tid + 256];
    __syncthreads();

    const int h = tid & 127, half = tid >> 7;
    const int d0 = half * 128;
    float acc[8] = {};
    for (int d = d0; d < d0 + 128; d += 4) {
        const float w0 = W[(d + 0) * HH + h];
        const float w1 = W[(d + 1) * HH + h];
        const float w2 = W[(d + 2) * HH + h];
        const float w3 = W[(d + 3) * HH + h];
#pragma unroll
        for (int r = 0; r < 8; ++r) {
            const float4 rv = *(const float4*)&rows[r][d];
            acc[r] = fmaf(rv.x, w0, fmaf(rv.y, w1, fmaf(rv.z, w2, fmaf(rv.w, w3, acc[r]))));
        }
    }
    if (half) {
#pragma unroll
        for (int r = 0; r < 8; ++r) partial[r][h] = acc[r];
    }
    __syncthreads();
    if (!half) {
        const float bv = bias[h];
#pragma unroll
        for (int r = 0; r < 8; ++r)
            outp[(size_t)(base + r) * HH + h] =
                __builtin_amdgcn_exp2f(C2LE * (acc[r] + partial[r][h] + bv));
    }
}

// ---- Kernel 2: P[b,n,m] = exp( sum_h w_h / (Ea_h*Eb_h + 1) ), w = -2v
//      (unnormalized; constant dropped). 4 h-terms share one rcp; all ops
//      packed over n-pairs (v_pk_fma_f32) via v2f.
__global__ __launch_bounds__(256) void scores_kernel(
    const float* __restrict__ Ea, const float* __restrict__ Eb,
    const float* __restrict__ v_w, float* __restrict__ P) {
    __shared__ float a_p[HH][34];   // a_p[h][n], pad 34: 2-way write alias only
    __shared__ float b_s[64 * HH];  // 32KB, XOR-swizzled rows
    __shared__ float w_s[HH];       // -2*v
    const int tid = threadIdx.x;
    const int m0 = blockIdx.x * 64, n0 = blockIdx.y * 32, b = blockIdx.z;

    for (int i = tid; i < 32 * 32; i += 256) {
        const int n = i >> 5, h4 = i & 31;
        const float4 v =
            *(const float4*)&Ea[((size_t)(b * NN + n0 + n)) * HH + h4 * 4];
        a_p[h4 * 4 + 0][n] = v.x;
        a_p[h4 * 4 + 1][n] = v.y;
        a_p[h4 * 4 + 2][n] = v.z;
        a_p[h4 * 4 + 3][n] = v.w;
    }
    for (int i = tid; i < 64 * 32; i += 256) {
        const int r = i >> 5, h4 = i & 31;
        *(float4*)&b_s[r * HH + ((h4 ^ (r & 7)) << 2)] =
            *(const float4*)&Eb[((size_t)(b * MM + m0 + r)) * HH + h4 * 4];
    }
    if (tid < HH) w_s[tid] = -2.0f * v_w[tid];
    __syncthreads();

    const int ml = tid & 63, ng = tid >> 6;
    const int mlx = ml & 7;
    const float* brow = &b_s[ml * HH];
    v2f acc[4] = {};
    for (int h4 = 0; h4 < 32; ++h4) {
        const float4 w4 = *(const float4*)&w_s[h4 * 4];            // broadcast
        const float4 b4 = *(const float4*)&brow[(h4 ^ mlx) << 2];  // swizzled
        const int hb = h4 * 4;
#pragma unroll
        for (int np = 0; np < 4; ++np) {
            const int nc = ng * 8 + np * 2;
            const v2f a0 = *(const v2f*)&a_p[hb + 0][nc];  // broadcast b64
            const v2f a1 = *(const v2f*)&a_p[hb + 1][nc];
            const v2f a2 = *(const v2f*)&a_p[hb + 2][nc];
            const v2f a3 = *(const v2f*)&a_p[hb + 3][nc];
            const v2f u0 = a0 * b4.x + 1.0f;   // v_pk_fma_f32
            const v2f u1 = a1 * b4.y + 1.0f;
            const v2f u2 = a2 * b4.z + 1.0f;
            const v2f u3 = a3 * b4.w + 1.0f;
            const v2f p01 = u0 * u1, p23 = u2 * u3;
            const v2f An = w4.x * u1 + w4.y * u0;
            const v2f Bn = w4.z * u3 + w4.w * u2;
            const v2f num = An * p23 + Bn * p01;
            const v2f Pp = p01 * p23;
            v2f r;
            r.x = __builtin_amdgcn_rcpf(Pp.x);
            r.y = __builtin_amdgcn_rcpf(Pp.y);
            acc[np] = num * r + acc[np];
        }
    }

    const size_t rowbase = (size_t)b * NN * MM + (size_t)n0 * MM + m0 + ml;
#pragma unroll
    for (int np = 0; np < 4; ++np) {
        P[rowbase + (size_t)(ng * 8 + np * 2 + 0) * MM] =
            __builtin_amdgcn_exp2f(acc[np].x * LOG2E);
        P[rowbase + (size_t)(ng * 8 + np * 2 + 1) * MM] =
            __builtin_amdgcn_exp2f(acc[np].y * LOG2E);
    }
}

// ---- Kernel 3: PV over an m-slice (MM/NQ). Wave w owns rows 4w..4w+3;
// lane owns d = lane*4 (float4). 4-deep k-register prefetch, no barriers.
template <int NQ>
__global__ __launch_bounds__(512) void attend_kernel(
    const float* __restrict__ P, const float* __restrict__ key,
    float* __restrict__ partial, float* __restrict__ psums) {
    constexpr int MQ = MM / NQ;
    __shared__ float p[ARO][MQ];
    const int tid = threadIdx.x;
    const int wave = tid >> 6, lane = tid & 63;
    const int n0 = blockIdx.x * ARO;
    const int mq = blockIdx.y;
    const int b  = blockIdx.z;
    const int m0 = mq * MQ;

    // stage P tile + row sums: wave w -> rows 4w..4w+3 (MQ/64 float2 per lane)
#pragma unroll
    for (int i = 0; i < 4; ++i) {
        const int r = wave * 4 + i;
        float s = 0.f;
#pragma unroll
        for (int c = 0; c < MQ / 128; ++c) {
            const float2 v = *(const float2*)
                &P[((size_t)(b * NN + n0 + r)) * MM + m0 + c * 128 + lane * 2];
            *(float2*)&p[r][c * 128 + lane * 2] = v;
            s += v.x + v.y;
        }
#pragma unroll
        for (int o = 32; o > 0; o >>= 1) s += __shfl_xor(s, o);
        if (lane == 0) psums[((size_t)mq * BB + b) * NN + n0 + r] = s;
    }
    __syncthreads();

    const int r0 = wave * 4;
    const float* kb = key + ((size_t)b * MM + m0) * DD + lane * 4;
    v4f a0 = 0.f, a1 = 0.f, a2 = 0.f, a3 = 0.f;
    v4f kc0, kc1, kc2, kc3;
    kc0 = *(const v4f*)&kb[0 * DD];
    kc1 = *(const v4f*)&kb[1 * DD];
    kc2 = *(const v4f*)&kb[2 * DD];
    kc3 = *(const v4f*)&kb[3 * DD];

#define PV_STEP(j, kreg)                       \
    {                                          \
        const float p0 = p[r0 + 0][m + (j)];   \
        const float p1 = p[r0 + 1][m + (j)];   \
        const float p2 = p[r0 + 2][m + (j)];   \
        const float p3 = p[r0 + 3][m + (j)];   \
        a0 = (kreg) * p0 + a0;                 \
        a1 = (kreg) * p1 + a1;                 \
        a2 = (kreg) * p2 + a2;                 \
        a3 = (kreg) * p3 + a3;                 \
    }

    int m = 0;
    for (; m < MQ - 4; m += 4) {
        // prefetch next group a full iteration ahead
        const v4f kn0 = *(const v4f*)&kb[(size_t)(m + 4) * DD];
        const v4f kn1 = *(const v4f*)&kb[(size_t)(m + 5) * DD];
        const v4f kn2 = *(const v4f*)&kb[(size_t)(m + 6) * DD];
        const v4f kn3 = *(const v4f*)&kb[(size_t)(m + 7) * DD];
        PV_STEP(0, kc0) PV_STEP(1, kc1) PV_STEP(2, kc2) PV_STEP(3, kc3)
        kc0 = kn0; kc1 = kn1; kc2 = kn2; kc3 = kn3;
    }
    PV_STEP(0, kc0) PV_STEP(1, kc1) PV_STEP(2, kc2) PV_STEP(3, kc3)
#undef PV_STEP

    const size_t base = (((size_t)mq * BB + b) * NN + n0 + r0) * DD + lane * 4;
    *(v4f*)&partial[base + 0 * DD] = a0;
    *(v4f*)&partial[base + 1 * DD] = a1;
    *(v4f*)&partial[base + 2 * DD] = a2;
    *(v4f*)&partial[base + 3 * DD] = a3;
}

// ---- Kernel 4: out[b,n,d] = sum_q partial[q][b,n,d] / sum_q psums[q][b,n]
template <int NQ>
__global__ __launch_bounds__(256) void combine_kernel(
    const float* __restrict__ partial, const float* __restrict__ psums,
    float* __restrict__ out) {
    const int n = blockIdx.x, b = blockIdx.y, d = threadIdx.x;
    float s = 0.f, a = 0.f;
#pragma unroll
    for (int q = 0; q < NQ; ++q) {
        s += psums[((size_t)q * BB + b) * NN + n];
        a += partial[(((size_t)q * BB + b) * NN + n) * DD + d];
    }
    out[((size_t)b * NN + n) * DD + d] = a * __builtin_amdgcn_rcpf(s);
}

extern "C" void kernel_launch(void* const* d_in, const int* in_sizes, int n_in,
                              void* d_out, int out_size, void* d_ws, size_t ws_size,
                              hipStream_t stream) {
    const float* query = (const float*)d_in[0];
    const float* key   = (const float*)d_in[1];
    const float* Wa_w  = (const float*)d_in[2];
    const float* Wa_b  = (const float*)d_in[3];
    const float* Wb_w  = (const float*)d_in[4];
    const float* Wb_b  = (const float*)d_in[5];
    const float* v_w   = (const float*)d_in[6];
    float* out = (float*)d_out;

    float* ws = (float*)d_ws;
    float* Ea = ws;                             // B*N*H
    float* Eb = Ea + BB * NN * HH;              // B*M*H
    float* P  = Eb + BB * MM * HH;              // B*N*M
    float* partial = P + (size_t)BB * NN * MM;  // NQ*B*N*D
    float* psums   = partial + (size_t)8 * BB * NN * DD;  // NQ*B*N
    const size_t base_f = (size_t)(BB * NN * HH) + BB * MM * HH + (size_t)BB * NN * MM;
    const size_t need8 =
        (base_f + (size_t)8 * BB * NN * DD + (size_t)8 * BB * NN + 2048) * sizeof(float);
    const size_t need4 =
        (base_f + (size_t)4 * BB * NN * DD + (size_t)4 * BB * NN + 2048) * sizeof(float);

    proj_kernel<<<dim3((BB * NN + BB * MM) / 8), dim3(256), 0, stream>>>(
        query, key, Wa_w, Wa_b, Wb_w, Wb_b, Ea, Eb);
    scores_kernel<<<dim3(MM / 64, NN / 32, BB), dim3(256), 0, stream>>>(
        Ea, Eb, v_w, P);
    if (ws_size >= need8) {
        attend_kernel<8><<<dim3(NN / ARO, 8, BB), dim3(512), 0, stream>>>(
            P, key, partial, psums);
        combine_kernel<8><<<dim3(NN, BB), dim3(256), 0, stream>>>(
            partial, psums, out);
    } else {
        // psums directly after the smaller partial
        float* psums4 = partial + (size_t)4 * BB * NN * DD;
        attend_kernel<4><<<dim3(NN / ARO, 4, BB), dim3(512), 0, stream>>>(
            P, key, partial, psums4);
        combine_kernel<4><<<dim3(NN, BB), dim3(256), 0, stream>>>(
            partial, psums4, out);
    }
    (void)need4;
}